// Round 10
// baseline (95.185 us; speedup 1.0000x reference)
//
#include <hip/hip_runtime.h>
#include <math.h>

// Shapes: S=4 B=8 N=2048 K=16 D=32 H=128; rows SBN=65536, rows/sb=2048.
// R10 = R7 (best measured: single kernel, 128-row tiles, 512 thr, grid 512)
// + three isolated fixes:
//  1. ek spread over ALL 8 waves (2k x 2h/thread, k wave-uniform) - no 4-wave
//     imbalance at the barrier (R7 lost ~1us there).
//  2. mu/tau staged to LDS (4KB) -> ek reads are wave-uniform broadcasts;
//     removes 32 global ~600cyc loads per ek thread + 67MB L2 re-stream.
//  3. barrier 3 deleted via R9-validated own-wave-rows trick (phase-2 rows
//     t>>3 within phase-1 wave rows t>>4; DS ops in-order per wave).
//     Barrier 2 stays (sEx overlays sX/sW cross-wave).
// LDS: region A max(sX 18432 + sW 17920, sEx 34816)=36352 + sWmt 32768
//      + sMT 4096 + sEk 4352 + sW2 256 = 77824 B -> 2 blocks/CU.
typedef _Float16 half_t;
typedef __attribute__((ext_vector_type(8))) _Float16 half8;
typedef __attribute__((ext_vector_type(2))) _Float16 half2_t;

#define EXP2F(x) __builtin_amdgcn_exp2f(x)
#define RCPF(x)  __builtin_amdgcn_rcpf(x)
#define C_SCALE 2.8853900817779268f   // 2*log2(e): tanh(z)=1-2/(1+2^(c*z))

__global__ __launch_bounds__(512, 4) void fused_kernel(
    const float* __restrict__ x, const float* __restrict__ mu,
    const float* __restrict__ tau, const float* __restrict__ W1,
    const float* __restrict__ b1, const float* __restrict__ W2,
    float* __restrict__ out) {
  // Region A: phase A = sX[128][36] f32 | sW (32x560B skewed Wx).
  //           phase B = sEx f16 [128][136] overlays it.
  __shared__ __align__(16) unsigned char sA[36352];
  __shared__ __align__(16) float sWmt[64][128];   // Wm rows 0..31, Wt 32..63
  __shared__ __align__(16) float sMT[1024];       // mu[16][32] then tau[16][32]
  __shared__ __align__(16) half_t sEk[16][136];   // 272B rows (16B-aligned)
  __shared__ __align__(16) half_t sW2[128];

  float (*sX)[36] = (float(*)[36])sA;
  unsigned char* sW = sA + 18432;

  int t = threadIdx.x;
  int row0 = blockIdx.x * 128;
  int sb = row0 >> 11;

  // ---- stage c*x tile: 128x32 = 1024 float4, coalesced ----
  const float4* x4 = (const float4*)(x + (size_t)row0 * 32);
#pragma unroll
  for (int i = 0; i < 2; ++i) {
    int j = i * 512 + t;                 // 0..1023
    int n = j >> 3, d4 = j & 7;
    float4 v = x4[j];
    v.x *= C_SCALE; v.y *= C_SCALE; v.z *= C_SCALE; v.w *= C_SCALE;
    *(float4*)&sX[n][d4 * 4] = v;
  }
  // ---- stage sW = Wx rows 0..31, bank-deconflicted (16B skew per 8 f4) ----
#pragma unroll
  for (int i = 0; i < 2; ++i) {
    int j = i * 512 + t;                 // 0..1023
    int d = j >> 5, f = j & 31;
    *(float4*)(sW + d * 560 + f * 16 + (f >> 3) * 16) = ((const float4*)W1)[j];
  }
  // ---- stage sWmt = W1 rows 32..95 (Wm then Wt), linear: 2048 float4 ----
  {
    const float4* wmt4 = (const float4*)(W1 + 32 * 128);
    float4* dst = (float4*)sWmt;
#pragma unroll
    for (int i = 0; i < 4; ++i) dst[i * 512 + t] = wmt4[i * 512 + t];
  }
  // ---- stage sMT = this sb's mu (512 f32) then tau (512 f32): 256 f4 ----
  if (t < 256) {
    const float* src = (t < 128) ? (mu + (size_t)sb * 512)
                                 : (tau + (size_t)sb * 512);
    ((float4*)sMT)[t] = ((const float4*)src)[t & 127];
  }
  // ---- stage w2h = f16(-2*W2) ----
  if (t < 16) {
    float4 a = ((const float4*)W2)[2 * t];
    float4 b = ((const float4*)W2)[2 * t + 1];
    half8 hv;
    hv[0] = (half_t)(-2.f * a.x); hv[1] = (half_t)(-2.f * a.y);
    hv[2] = (half_t)(-2.f * a.z); hv[3] = (half_t)(-2.f * a.w);
    hv[4] = (half_t)(-2.f * b.x); hv[5] = (half_t)(-2.f * b.y);
    hv[6] = (half_t)(-2.f * b.z); hv[7] = (half_t)(-2.f * b.w);
    *(half8*)&sW2[t * 8] = hv;
  }
  __syncthreads();   // barrier 1: sX, sW, sWmt, sMT, sW2 staged

  // ---- ek -> sEk (f16): all 8 waves, 2 k x 2 h per thread.
  //      k0 = (t>>6)*2 is WAVE-UNIFORM -> mu/tau LDS reads broadcast (free).
  //      Per-(k,h) chain: d ascending, mu-then-tau per d (bit-identical to
  //      R0/R4/R6/R7 ek).
  {
    int k0 = (t >> 6) * 2;               // wave-uniform
    int h0 = (t & 63) * 2;
    const float* sMu  = sMT;             // [16][32]
    const float* sTau = sMT + 512;
    float2 bb = *(const float2*)(b1 + h0);
    float a00 = bb.x, a01 = bb.y;        // k0, h0 / h0+1
    float a10 = bb.x, a11 = bb.y;        // k0+1
#pragma unroll 2
    for (int d4 = 0; d4 < 8; ++d4) {
      float4 m0 = *(const float4*)(sMu  + k0 * 32 + d4 * 4);
      float4 m1 = *(const float4*)(sMu  + (k0 + 1) * 32 + d4 * 4);
      float4 t0 = *(const float4*)(sTau + k0 * 32 + d4 * 4);
      float4 t1 = *(const float4*)(sTau + (k0 + 1) * 32 + d4 * 4);
      float m0a[4] = {m0.x, m0.y, m0.z, m0.w};
      float m1a[4] = {m1.x, m1.y, m1.z, m1.w};
      float t0a[4] = {t0.x, t0.y, t0.z, t0.w};
      float t1a[4] = {t1.x, t1.y, t1.z, t1.w};
#pragma unroll
      for (int dd = 0; dd < 4; ++dd) {
        int d = d4 * 4 + dd;
        float2 wm = *(const float2*)(&sWmt[d][h0]);
        float2 wt = *(const float2*)(&sWmt[32 + d][h0]);
        a00 = fmaf(m0a[dd], wm.x, a00); a00 = fmaf(t0a[dd], wt.x, a00);
        a01 = fmaf(m0a[dd], wm.y, a01); a01 = fmaf(t0a[dd], wt.y, a01);
        a10 = fmaf(m1a[dd], wm.x, a10); a10 = fmaf(t1a[dd], wt.x, a10);
        a11 = fmaf(m1a[dd], wm.y, a11); a11 = fmaf(t1a[dd], wt.y, a11);
      }
    }
    half2_t e0, e1;
    e0[0] = (half_t)EXP2F(C_SCALE * a00); e0[1] = (half_t)EXP2F(C_SCALE * a01);
    e1[0] = (half_t)EXP2F(C_SCALE * a10); e1[1] = (half_t)EXP2F(C_SCALE * a11);
    *(half2_t*)&sEk[k0][h0] = e0;
    *(half2_t*)&sEk[k0 + 1][h0] = e1;
  }

  // ---- phase 1: hx GEMM from LDS -> exp2 -> f16 regs. 4 rows x 8 h/thread.
  int hg = t & 15, rg = t >> 4;          // hg 0..15, rg 0..31
  int h0 = hg * 8, r0 = rg * 4;
  half8 hv[4];
  {
    const unsigned char* wbase = sW + hg * 32 + (hg >> 2) * 16;
    float acc[4][8];
#pragma unroll
    for (int j = 0; j < 4; ++j)
#pragma unroll
      for (int l = 0; l < 8; ++l) acc[j][l] = 0.f;
#pragma unroll
    for (int d4 = 0; d4 < 8; ++d4) {
      float xc[4][4];                    // [j][dd], static indices
#pragma unroll
      for (int j = 0; j < 4; ++j) {
        float4 xv = *(const float4*)&sX[r0 + j][d4 * 4];
        xc[j][0] = xv.x; xc[j][1] = xv.y; xc[j][2] = xv.z; xc[j][3] = xv.w;
      }
#pragma unroll
      for (int dd = 0; dd < 4; ++dd) {
        int d = d4 * 4 + dd;
        float4 wa = *(const float4*)(wbase + d * 560);
        float4 wb = *(const float4*)(wbase + d * 560 + 16);
        float w[8] = {wa.x, wa.y, wa.z, wa.w, wb.x, wb.y, wb.z, wb.w};
#pragma unroll
        for (int j = 0; j < 4; ++j) {
          float xv = xc[j][dd];
#pragma unroll
          for (int l = 0; l < 8; ++l) acc[j][l] = fmaf(xv, w[l], acc[j][l]);
        }
      }
    }
#pragma unroll
    for (int j = 0; j < 4; ++j)
#pragma unroll
      for (int l = 0; l < 8; ++l) hv[j][l] = (half_t)EXP2F(acc[j][l]);
  }
  __syncthreads();   // barrier 2: all sX/sW reads done (overlay safe) AND
                     // sEk writes visible to all waves

  half_t (*sEx)[136] = (half_t(*)[136])sA;
#pragma unroll
  for (int j = 0; j < 4; ++j) *(half8*)&sEx[r0 + j][h0] = hv[j];
  // Own-wave rows: phase-2 reads rows [16w,16w+16) written above by the same
  // wave; DS ops are in-order per wave -> compiler fence only (R9-validated).
  asm volatile("" ::: "memory");

  // ---- phase 2: 2 rows x 2 k per thread, 5 f16 reads/h8, pairwise rcp ----
  int kg = t & 7, rg2 = t >> 3;          // rg2 0..63; rows [16w,16w+16)
  int rp = rg2 * 2, k0p = kg * 2;
  const half_t* exr0 = &sEx[rp][0];
  const half_t* exr1 = &sEx[rp + 1][0];
  const half_t* ekr0 = &sEk[k0p][0];
  const half_t* ekr1 = &sEk[k0p + 1][0];
  float a00 = 0.f, a01 = 0.f, a10 = 0.f, a11 = 0.f;
#pragma unroll
  for (int h8 = 0; h8 < 16; ++h8) {
    half8 ex0h = *(const half8*)(exr0 + h8 * 8);
    half8 ex1h = *(const half8*)(exr1 + h8 * 8);
    half8 ek0h = *(const half8*)(ekr0 + h8 * 8);
    half8 ek1h = *(const half8*)(ekr1 + h8 * 8);
    half8 wvh  = *(const half8*)(&sW2[h8 * 8]);
    float e0[8], e1[8], f0[8], f1[8], w[8];
#pragma unroll
    for (int j = 0; j < 8; ++j) {
      e0[j] = (float)ex0h[j]; e1[j] = (float)ex1h[j];
      f0[j] = (float)ek0h[j]; f1[j] = (float)ek1h[j];
      w[j]  = (float)wvh[j];
    }
#pragma unroll
    for (int p = 0; p < 4; ++p) {
      int j0 = 2 * p, j1 = 2 * p + 1;
      {
        float A = fmaf(e0[j0], f0[j0], 1.f), B = fmaf(e0[j1], f0[j1], 1.f);
        a00 = fmaf(fmaf(w[j0], B, w[j1] * A), RCPF(A * B), a00);
      }
      {
        float A = fmaf(e0[j0], f1[j0], 1.f), B = fmaf(e0[j1], f1[j1], 1.f);
        a01 = fmaf(fmaf(w[j0], B, w[j1] * A), RCPF(A * B), a01);
      }
      {
        float A = fmaf(e1[j0], f0[j0], 1.f), B = fmaf(e1[j1], f0[j1], 1.f);
        a10 = fmaf(fmaf(w[j0], B, w[j1] * A), RCPF(A * B), a10);
      }
      {
        float A = fmaf(e1[j0], f1[j0], 1.f), B = fmaf(e1[j1], f1[j1], 1.f);
        a11 = fmaf(fmaf(w[j0], B, w[j1] * A), RCPF(A * B), a11);
      }
    }
  }

  // ---- softmax over k: 2 k in-thread x 8 kg-lanes (shuffle width 8) ----
  const float l2e = 1.4426950408889634f;
  {
    float m = fmaxf(a00, a01);
#pragma unroll
    for (int s = 1; s < 8; s <<= 1) m = fmaxf(m, __shfl_xor(m, s, 8));
    float p0 = EXP2F((a00 - m) * l2e), p1 = EXP2F((a01 - m) * l2e);
    float sum = p0 + p1;
#pragma unroll
    for (int s = 1; s < 8; s <<= 1) sum += __shfl_xor(sum, s, 8);
    float inv = RCPF(sum);
    float2 o = make_float2(p0 * inv, p1 * inv);
    *(float2*)&out[(size_t)(row0 + rp) * 16 + k0p] = o;
  }
  {
    float m = fmaxf(a10, a11);
#pragma unroll
    for (int s = 1; s < 8; s <<= 1) m = fmaxf(m, __shfl_xor(m, s, 8));
    float p0 = EXP2F((a10 - m) * l2e), p1 = EXP2F((a11 - m) * l2e);
    float sum = p0 + p1;
#pragma unroll
    for (int s = 1; s < 8; s <<= 1) sum += __shfl_xor(sum, s, 8);
    float inv = RCPF(sum);
    float2 o = make_float2(p0 * inv, p1 * inv);
    *(float2*)&out[(size_t)(row0 + rp + 1) * 16 + k0p] = o;
  }
}

// ---------------------------------------------------------------------------
extern "C" void kernel_launch(void* const* d_in, const int* in_sizes, int n_in,
                              void* d_out, int out_size, void* d_ws, size_t ws_size,
                              hipStream_t stream) {
  const float* x   = (const float*)d_in[0];
  const float* mu  = (const float*)d_in[1];
  const float* tau = (const float*)d_in[2];
  const float* W1  = (const float*)d_in[3];
  const float* b1  = (const float*)d_in[4];
  const float* W2  = (const float*)d_in[5];
  // b2 (d_in[6]) and sum(W2) are k-uniform -> cancelled by softmax.
  float* out = (float*)d_out;
  (void)in_sizes; (void)n_in; (void)out_size; (void)d_ws; (void)ws_size;

  fused_kernel<<<512, 512, 0, stream>>>(x, mu, tau, W1, b1, W2, out);
}

// Round 11
// 92.937 us; speedup vs baseline: 1.0242x; 1.0242x over previous
//
#include <hip/hip_runtime.h>
#include <math.h>

// Shapes: S=4 B=8 N=2048 K=16 D=32 H=128; rows SBN=65536, rows/sb=2048.
// R11 = R7 verbatim (measured-best: 91.4us total, ~38us kernel) + ONE change:
// barrier 3 deleted via the own-wave-rows property (phase-2 rows t>>3 are a
// subset of phase-1 wave rows t>>4; DS ops are in-order per wave), validated
// correct in R9 and R10. Everything else byte-identical to R7.
// LDS: region A max(sX 18432 + sW 17920, sEx 34816)=36352 + sWmt 32768
//      + sEk 4352 + sW2 256 = 73728 B -> 2 blocks/CU, grid 512 = exact fill.
typedef _Float16 half_t;
typedef __attribute__((ext_vector_type(8))) _Float16 half8;
typedef __attribute__((ext_vector_type(4))) _Float16 half4;

#define EXP2F(x) __builtin_amdgcn_exp2f(x)
#define RCPF(x)  __builtin_amdgcn_rcpf(x)
#define C_SCALE 2.8853900817779268f   // 2*log2(e): tanh(z)=1-2/(1+2^(c*z))

__global__ __launch_bounds__(512, 4) void fused_kernel(
    const float* __restrict__ x, const float* __restrict__ mu,
    const float* __restrict__ tau, const float* __restrict__ W1,
    const float* __restrict__ b1, const float* __restrict__ W2,
    float* __restrict__ out) {
  // Region A (36352 B): phase A = sX[128][36] f32 | sW (32x560B skewed Wx).
  //                     phase B = sEx f16 [128][136] overlays it.
  __shared__ __align__(16) unsigned char sA[36352];
  __shared__ __align__(16) float sWmt[64][128];   // Wm rows 0..31, Wt 32..63
  __shared__ __align__(16) half_t sEk[16][136];   // 4352 B
  __shared__ __align__(16) half_t sW2[128];       // 256 B

  float (*sX)[36] = (float(*)[36])sA;
  unsigned char* sW = sA + 18432;

  int t = threadIdx.x;
  int row0 = blockIdx.x * 128;
  int sb = row0 >> 11;

  // ---- stage c*x tile: 128x32 = 1024 float4, coalesced ----
  const float4* x4 = (const float4*)(x + (size_t)row0 * 32);
#pragma unroll
  for (int i = 0; i < 2; ++i) {
    int j = i * 512 + t;                 // 0..1023
    int n = j >> 3, d4 = j & 7;
    float4 v = x4[j];
    v.x *= C_SCALE; v.y *= C_SCALE; v.z *= C_SCALE; v.w *= C_SCALE;
    *(float4*)&sX[n][d4 * 4] = v;
  }
  // ---- stage sW = Wx rows 0..31, bank-deconflicted (16B skew per 8 f4) ----
#pragma unroll
  for (int i = 0; i < 2; ++i) {
    int j = i * 512 + t;                 // 0..1023
    int d = j >> 5, f = j & 31;
    *(float4*)(sW + d * 560 + f * 16 + (f >> 3) * 16) = ((const float4*)W1)[j];
  }
  // ---- stage sWmt = W1 rows 32..95 (Wm then Wt), linear: 2048 float4 ----
  {
    const float4* wmt4 = (const float4*)(W1 + 32 * 128);
    float4* dst = (float4*)sWmt;
#pragma unroll
    for (int i = 0; i < 4; ++i) dst[i * 512 + t] = wmt4[i * 512 + t];
  }
  // ---- stage w2h = f16(-2*W2) ----
  if (t < 16) {
    float4 a = ((const float4*)W2)[2 * t];
    float4 b = ((const float4*)W2)[2 * t + 1];
    half8 hv;
    hv[0] = (half_t)(-2.f * a.x); hv[1] = (half_t)(-2.f * a.y);
    hv[2] = (half_t)(-2.f * a.z); hv[3] = (half_t)(-2.f * a.w);
    hv[4] = (half_t)(-2.f * b.x); hv[5] = (half_t)(-2.f * b.y);
    hv[6] = (half_t)(-2.f * b.z); hv[7] = (half_t)(-2.f * b.w);
    *(half8*)&sW2[t * 8] = hv;
  }
  __syncthreads();   // barrier 1: sX, sW, sWmt, sW2 staged

  // ---- ek -> sEk (f16): 256 threads x (2 k x 4 h); W reads from LDS,
  //      reused across the 2 k. Per-h chain: d ascending, mu-then-tau per d
  //      (bit-identical to R0/R4/R6/R7 ek).
  if (t < 256) {
    int k0 = (t >> 5) * 2, h0 = (t & 31) * 4;
    const float4* mu4a  = (const float4*)(mu  + ((size_t)sb * 16 + k0) * 32);
    const float4* tau4a = (const float4*)(tau + ((size_t)sb * 16 + k0) * 32);
    const float4* mu4b  = mu4a + 8;      // row k0+1
    const float4* tau4b = tau4a + 8;
    float acc0[4], acc1[4];
    {
      float4 ba = *(const float4*)(b1 + h0);
      acc0[0] = ba.x; acc0[1] = ba.y; acc0[2] = ba.z; acc0[3] = ba.w;
      acc1[0] = ba.x; acc1[1] = ba.y; acc1[2] = ba.z; acc1[3] = ba.w;
    }
    const float* Wm = (const float*)sWmt + h0;
    const float* Wt = (const float*)sWmt + 32 * 128 + h0;
#pragma unroll 2
    for (int d4 = 0; d4 < 8; ++d4) {
      float4 ma = mu4a[d4], ta = tau4a[d4];
      float4 mb = mu4b[d4], tb = tau4b[d4];
      float mva[4] = {ma.x, ma.y, ma.z, ma.w};
      float tva[4] = {ta.x, ta.y, ta.z, ta.w};
      float mvb[4] = {mb.x, mb.y, mb.z, mb.w};
      float tvb[4] = {tb.x, tb.y, tb.z, tb.w};
#pragma unroll
      for (int dd = 0; dd < 4; ++dd) {
        int d = d4 * 4 + dd;
        float4 wm = *(const float4*)(Wm + d * 128);
        float4 wt = *(const float4*)(Wt + d * 128);
        float wmv[4] = {wm.x, wm.y, wm.z, wm.w};
        float wtv[4] = {wt.x, wt.y, wt.z, wt.w};
#pragma unroll
        for (int l = 0; l < 4; ++l) {
          acc0[l] = fmaf(mva[dd], wmv[l], acc0[l]);
          acc0[l] = fmaf(tva[dd], wtv[l], acc0[l]);
          acc1[l] = fmaf(mvb[dd], wmv[l], acc1[l]);
          acc1[l] = fmaf(tvb[dd], wtv[l], acc1[l]);
        }
      }
    }
    half4 h0v, h1v;
#pragma unroll
    for (int l = 0; l < 4; ++l) {
      h0v[l] = (half_t)EXP2F(C_SCALE * acc0[l]);
      h1v[l] = (half_t)EXP2F(C_SCALE * acc1[l]);
    }
    *(half4*)&sEk[k0][h0] = h0v;
    *(half4*)&sEk[k0 + 1][h0] = h1v;
  }

  // ---- phase 1: hx GEMM from LDS -> exp2 -> f16 regs. 4 rows x 8 h/thread.
  int hg = t & 15, rg = t >> 4;          // hg 0..15, rg 0..31
  int h0 = hg * 8, r0 = rg * 4;
  half8 hv[4];
  {
    const unsigned char* wbase = sW + hg * 32 + (hg >> 2) * 16;
    float acc[4][8];
#pragma unroll
    for (int j = 0; j < 4; ++j)
#pragma unroll
      for (int l = 0; l < 8; ++l) acc[j][l] = 0.f;
#pragma unroll
    for (int d4 = 0; d4 < 8; ++d4) {
      float xc[4][4];                    // [j][dd], static indices
#pragma unroll
      for (int j = 0; j < 4; ++j) {
        float4 xv = *(const float4*)&sX[r0 + j][d4 * 4];
        xc[j][0] = xv.x; xc[j][1] = xv.y; xc[j][2] = xv.z; xc[j][3] = xv.w;
      }
#pragma unroll
      for (int dd = 0; dd < 4; ++dd) {
        int d = d4 * 4 + dd;
        float4 wa = *(const float4*)(wbase + d * 560);
        float4 wb = *(const float4*)(wbase + d * 560 + 16);
        float w[8] = {wa.x, wa.y, wa.z, wa.w, wb.x, wb.y, wb.z, wb.w};
#pragma unroll
        for (int j = 0; j < 4; ++j) {
          float xv = xc[j][dd];
#pragma unroll
          for (int l = 0; l < 8; ++l) acc[j][l] = fmaf(xv, w[l], acc[j][l]);
        }
      }
    }
#pragma unroll
    for (int j = 0; j < 4; ++j)
#pragma unroll
      for (int l = 0; l < 8; ++l) hv[j][l] = (half_t)EXP2F(acc[j][l]);
  }
  __syncthreads();   // barrier 2: all sX/sW/sWmt reads done (overlay safe)
                     // AND sEk writes visible to all waves

  half_t (*sEx)[136] = (half_t(*)[136])sA;
#pragma unroll
  for (int j = 0; j < 4; ++j) *(half8*)&sEx[r0 + j][h0] = hv[j];
  // barrier 3 DELETED (the one R11 change): phase-2 reads rows
  // [16w,16w+16) written above by the same wave; DS ops are in-order per
  // wave (R9/R10-validated). Compiler fence only.
  asm volatile("" ::: "memory");

  // ---- phase 2: 2 rows x 2 k per thread, 5 f16 reads/h8, pairwise rcp ----
  int kg = t & 7, rg2 = t >> 3;          // rg2 0..63; rows [16w,16w+16)
  int rp = rg2 * 2, k0p = kg * 2;
  const half_t* exr0 = &sEx[rp][0];
  const half_t* exr1 = &sEx[rp + 1][0];
  const half_t* ekr0 = &sEk[k0p][0];
  const half_t* ekr1 = &sEk[k0p + 1][0];
  float a00 = 0.f, a01 = 0.f, a10 = 0.f, a11 = 0.f;
#pragma unroll
  for (int h8 = 0; h8 < 16; ++h8) {
    half8 ex0h = *(const half8*)(exr0 + h8 * 8);
    half8 ex1h = *(const half8*)(exr1 + h8 * 8);
    half8 ek0h = *(const half8*)(ekr0 + h8 * 8);
    half8 ek1h = *(const half8*)(ekr1 + h8 * 8);
    half8 wvh  = *(const half8*)(&sW2[h8 * 8]);
    float e0[8], e1[8], f0[8], f1[8], w[8];
#pragma unroll
    for (int j = 0; j < 8; ++j) {
      e0[j] = (float)ex0h[j]; e1[j] = (float)ex1h[j];
      f0[j] = (float)ek0h[j]; f1[j] = (float)ek1h[j];
      w[j]  = (float)wvh[j];
    }
#pragma unroll
    for (int p = 0; p < 4; ++p) {
      int j0 = 2 * p, j1 = 2 * p + 1;
      {
        float A = fmaf(e0[j0], f0[j0], 1.f), B = fmaf(e0[j1], f0[j1], 1.f);
        a00 = fmaf(fmaf(w[j0], B, w[j1] * A), RCPF(A * B), a00);
      }
      {
        float A = fmaf(e0[j0], f1[j0], 1.f), B = fmaf(e0[j1], f1[j1], 1.f);
        a01 = fmaf(fmaf(w[j0], B, w[j1] * A), RCPF(A * B), a01);
      }
      {
        float A = fmaf(e1[j0], f0[j0], 1.f), B = fmaf(e1[j1], f0[j1], 1.f);
        a10 = fmaf(fmaf(w[j0], B, w[j1] * A), RCPF(A * B), a10);
      }
      {
        float A = fmaf(e1[j0], f1[j0], 1.f), B = fmaf(e1[j1], f1[j1], 1.f);
        a11 = fmaf(fmaf(w[j0], B, w[j1] * A), RCPF(A * B), a11);
      }
    }
  }

  // ---- softmax over k: 2 k in-thread x 8 kg-lanes (shuffle width 8) ----
  const float l2e = 1.4426950408889634f;
  {
    float m = fmaxf(a00, a01);
#pragma unroll
    for (int s = 1; s < 8; s <<= 1) m = fmaxf(m, __shfl_xor(m, s, 8));
    float p0 = EXP2F((a00 - m) * l2e), p1 = EXP2F((a01 - m) * l2e);
    float sum = p0 + p1;
#pragma unroll
    for (int s = 1; s < 8; s <<= 1) sum += __shfl_xor(sum, s, 8);
    float inv = RCPF(sum);
    float2 o = make_float2(p0 * inv, p1 * inv);
    *(float2*)&out[(size_t)(row0 + rp) * 16 + k0p] = o;
  }
  {
    float m = fmaxf(a10, a11);
#pragma unroll
    for (int s = 1; s < 8; s <<= 1) m = fmaxf(m, __shfl_xor(m, s, 8));
    float p0 = EXP2F((a10 - m) * l2e), p1 = EXP2F((a11 - m) * l2e);
    float sum = p0 + p1;
#pragma unroll
    for (int s = 1; s < 8; s <<= 1) sum += __shfl_xor(sum, s, 8);
    float inv = RCPF(sum);
    float2 o = make_float2(p0 * inv, p1 * inv);
    *(float2*)&out[(size_t)(row0 + rp + 1) * 16 + k0p] = o;
  }
}

// ---------------------------------------------------------------------------
extern "C" void kernel_launch(void* const* d_in, const int* in_sizes, int n_in,
                              void* d_out, int out_size, void* d_ws, size_t ws_size,
                              hipStream_t stream) {
  const float* x   = (const float*)d_in[0];
  const float* mu  = (const float*)d_in[1];
  const float* tau = (const float*)d_in[2];
  const float* W1  = (const float*)d_in[3];
  const float* b1  = (const float*)d_in[4];
  const float* W2  = (const float*)d_in[5];
  // b2 (d_in[6]) and sum(W2) are k-uniform -> cancelled by softmax.
  float* out = (float*)d_out;
  (void)in_sizes; (void)n_in; (void)out_size; (void)d_ws; (void)ws_size;

  fused_kernel<<<512, 512, 0, stream>>>(x, mu, tau, W1, b1, W2, out);
}

// Round 12
// 91.693 us; speedup vs baseline: 1.0381x; 1.0136x over previous
//
#include <hip/hip_runtime.h>
#include <math.h>

// Shapes: S=4 B=8 N=2048 K=16 D=32 H=128; rows SBN=65536, rows/sb=2048.
// R12 = R7 verbatim (measured-best across 12 rounds: 91.4us total).
// Session ledger: R7 91.4 | R11 (no barrier3) 92.9 | R6/R9 split 93.1/93.8 |
// R8/R10 95.6/95.2 | fused-ek-LDS-conflict variants 97+. Fixed harness cost
// ~54us (fill ~41 + 2 dispatch boundaries ~13); kernel ~37-38us, latency-
// bound at 16 waves/CU (VALUBusy ~44%). Remaining levers are EV<=0:
// shfl-reduce = DS-pipe ops (costs more than the ds_reads it saves);
// f16/packed phase-2 has an inf*0=NaN overflow path (A=1+e*f > f16 max).
// LDS: region A max(sX 18432 + sW 17920, sEx 34816)=36352 + sWmt 32768
//      + sEk 4352 + sW2 256 = 73728 B -> 2 blocks/CU, grid 512 = exact fill.
typedef _Float16 half_t;
typedef __attribute__((ext_vector_type(8))) _Float16 half8;
typedef __attribute__((ext_vector_type(4))) _Float16 half4;

#define EXP2F(x) __builtin_amdgcn_exp2f(x)
#define RCPF(x)  __builtin_amdgcn_rcpf(x)
#define C_SCALE 2.8853900817779268f   // 2*log2(e): tanh(z)=1-2/(1+2^(c*z))

__global__ __launch_bounds__(512, 4) void fused_kernel(
    const float* __restrict__ x, const float* __restrict__ mu,
    const float* __restrict__ tau, const float* __restrict__ W1,
    const float* __restrict__ b1, const float* __restrict__ W2,
    float* __restrict__ out) {
  // Region A (36352 B): phase A = sX[128][36] f32 | sW (32x560B skewed Wx).
  //                     phase B = sEx f16 [128][136] overlays it.
  __shared__ __align__(16) unsigned char sA[36352];
  __shared__ __align__(16) float sWmt[64][128];   // Wm rows 0..31, Wt 32..63
  __shared__ __align__(16) half_t sEk[16][136];   // 4352 B
  __shared__ __align__(16) half_t sW2[128];       // 256 B

  float (*sX)[36] = (float(*)[36])sA;
  unsigned char* sW = sA + 18432;

  int t = threadIdx.x;
  int row0 = blockIdx.x * 128;
  int sb = row0 >> 11;

  // ---- stage c*x tile: 128x32 = 1024 float4, coalesced ----
  const float4* x4 = (const float4*)(x + (size_t)row0 * 32);
#pragma unroll
  for (int i = 0; i < 2; ++i) {
    int j = i * 512 + t;                 // 0..1023
    int n = j >> 3, d4 = j & 7;
    float4 v = x4[j];
    v.x *= C_SCALE; v.y *= C_SCALE; v.z *= C_SCALE; v.w *= C_SCALE;
    *(float4*)&sX[n][d4 * 4] = v;
  }
  // ---- stage sW = Wx rows 0..31, bank-deconflicted (16B skew per 8 f4) ----
#pragma unroll
  for (int i = 0; i < 2; ++i) {
    int j = i * 512 + t;                 // 0..1023
    int d = j >> 5, f = j & 31;
    *(float4*)(sW + d * 560 + f * 16 + (f >> 3) * 16) = ((const float4*)W1)[j];
  }
  // ---- stage sWmt = W1 rows 32..95 (Wm then Wt), linear: 2048 float4 ----
  {
    const float4* wmt4 = (const float4*)(W1 + 32 * 128);
    float4* dst = (float4*)sWmt;
#pragma unroll
    for (int i = 0; i < 4; ++i) dst[i * 512 + t] = wmt4[i * 512 + t];
  }
  // ---- stage w2h = f16(-2*W2) ----
  if (t < 16) {
    float4 a = ((const float4*)W2)[2 * t];
    float4 b = ((const float4*)W2)[2 * t + 1];
    half8 hv;
    hv[0] = (half_t)(-2.f * a.x); hv[1] = (half_t)(-2.f * a.y);
    hv[2] = (half_t)(-2.f * a.z); hv[3] = (half_t)(-2.f * a.w);
    hv[4] = (half_t)(-2.f * b.x); hv[5] = (half_t)(-2.f * b.y);
    hv[6] = (half_t)(-2.f * b.z); hv[7] = (half_t)(-2.f * b.w);
    *(half8*)&sW2[t * 8] = hv;
  }
  __syncthreads();   // barrier 1: sX, sW, sWmt, sW2 staged

  // ---- ek -> sEk (f16): 256 threads x (2 k x 4 h); W reads from LDS,
  //      reused across the 2 k. Per-h chain: d ascending, mu-then-tau per d
  //      (bit-identical to R0/R4/R6 ek). Waves 4-7 skip straight to phase 1.
  if (t < 256) {
    int k0 = (t >> 5) * 2, h0 = (t & 31) * 4;
    const float4* mu4a  = (const float4*)(mu  + ((size_t)sb * 16 + k0) * 32);
    const float4* tau4a = (const float4*)(tau + ((size_t)sb * 16 + k0) * 32);
    const float4* mu4b  = mu4a + 8;      // row k0+1
    const float4* tau4b = tau4a + 8;
    float acc0[4], acc1[4];
    {
      float4 ba = *(const float4*)(b1 + h0);
      acc0[0] = ba.x; acc0[1] = ba.y; acc0[2] = ba.z; acc0[3] = ba.w;
      acc1[0] = ba.x; acc1[1] = ba.y; acc1[2] = ba.z; acc1[3] = ba.w;
    }
    const float* Wm = (const float*)sWmt + h0;
    const float* Wt = (const float*)sWmt + 32 * 128 + h0;
#pragma unroll 2
    for (int d4 = 0; d4 < 8; ++d4) {
      float4 ma = mu4a[d4], ta = tau4a[d4];
      float4 mb = mu4b[d4], tb = tau4b[d4];
      float mva[4] = {ma.x, ma.y, ma.z, ma.w};
      float tva[4] = {ta.x, ta.y, ta.z, ta.w};
      float mvb[4] = {mb.x, mb.y, mb.z, mb.w};
      float tvb[4] = {tb.x, tb.y, tb.z, tb.w};
#pragma unroll
      for (int dd = 0; dd < 4; ++dd) {
        int d = d4 * 4 + dd;
        float4 wm = *(const float4*)(Wm + d * 128);
        float4 wt = *(const float4*)(Wt + d * 128);
        float wmv[4] = {wm.x, wm.y, wm.z, wm.w};
        float wtv[4] = {wt.x, wt.y, wt.z, wt.w};
#pragma unroll
        for (int l = 0; l < 4; ++l) {
          acc0[l] = fmaf(mva[dd], wmv[l], acc0[l]);
          acc0[l] = fmaf(tva[dd], wtv[l], acc0[l]);
          acc1[l] = fmaf(mvb[dd], wmv[l], acc1[l]);
          acc1[l] = fmaf(tvb[dd], wtv[l], acc1[l]);
        }
      }
    }
    half4 h0v, h1v;
#pragma unroll
    for (int l = 0; l < 4; ++l) {
      h0v[l] = (half_t)EXP2F(C_SCALE * acc0[l]);
      h1v[l] = (half_t)EXP2F(C_SCALE * acc1[l]);
    }
    *(half4*)&sEk[k0][h0] = h0v;
    *(half4*)&sEk[k0 + 1][h0] = h1v;
  }

  // ---- phase 1: hx GEMM from LDS -> exp2 -> f16 regs. 4 rows x 8 h/thread.
  int hg = t & 15, rg = t >> 4;          // hg 0..15, rg 0..31
  int h0 = hg * 8, r0 = rg * 4;
  half8 hv[4];
  {
    const unsigned char* wbase = sW + hg * 32 + (hg >> 2) * 16;
    float acc[4][8];
#pragma unroll
    for (int j = 0; j < 4; ++j)
#pragma unroll
      for (int l = 0; l < 8; ++l) acc[j][l] = 0.f;
#pragma unroll
    for (int d4 = 0; d4 < 8; ++d4) {
      float xc[4][4];                    // [j][dd], static indices
#pragma unroll
      for (int j = 0; j < 4; ++j) {
        float4 xv = *(const float4*)&sX[r0 + j][d4 * 4];
        xc[j][0] = xv.x; xc[j][1] = xv.y; xc[j][2] = xv.z; xc[j][3] = xv.w;
      }
#pragma unroll
      for (int dd = 0; dd < 4; ++dd) {
        int d = d4 * 4 + dd;
        float4 wa = *(const float4*)(wbase + d * 560);
        float4 wb = *(const float4*)(wbase + d * 560 + 16);
        float w[8] = {wa.x, wa.y, wa.z, wa.w, wb.x, wb.y, wb.z, wb.w};
#pragma unroll
        for (int j = 0; j < 4; ++j) {
          float xv = xc[j][dd];
#pragma unroll
          for (int l = 0; l < 8; ++l) acc[j][l] = fmaf(xv, w[l], acc[j][l]);
        }
      }
    }
#pragma unroll
    for (int j = 0; j < 4; ++j)
#pragma unroll
      for (int l = 0; l < 8; ++l) hv[j][l] = (half_t)EXP2F(acc[j][l]);
  }
  __syncthreads();   // barrier 2: all sX/sW/sWmt reads done (overlay safe)
                     // AND sEk writes visible to all waves

  half_t (*sEx)[136] = (half_t(*)[136])sA;
#pragma unroll
  for (int j = 0; j < 4; ++j) *(half8*)&sEx[r0 + j][h0] = hv[j];
  __syncthreads();   // barrier 3: sEx visible (R7 exact; removing it measured
                     // within noise but slightly worse in R11)

  // ---- phase 2: 2 rows x 2 k per thread, 5 f16 reads/h8, pairwise rcp ----
  int kg = t & 7, rg2 = t >> 3;          // rg2 0..63
  int rp = rg2 * 2, k0p = kg * 2;
  const half_t* exr0 = &sEx[rp][0];
  const half_t* exr1 = &sEx[rp + 1][0];
  const half_t* ekr0 = &sEk[k0p][0];
  const half_t* ekr1 = &sEk[k0p + 1][0];
  float a00 = 0.f, a01 = 0.f, a10 = 0.f, a11 = 0.f;
#pragma unroll
  for (int h8 = 0; h8 < 16; ++h8) {
    half8 ex0h = *(const half8*)(exr0 + h8 * 8);
    half8 ex1h = *(const half8*)(exr1 + h8 * 8);
    half8 ek0h = *(const half8*)(ekr0 + h8 * 8);
    half8 ek1h = *(const half8*)(ekr1 + h8 * 8);
    half8 wvh  = *(const half8*)(&sW2[h8 * 8]);
    float e0[8], e1[8], f0[8], f1[8], w[8];
#pragma unroll
    for (int j = 0; j < 8; ++j) {
      e0[j] = (float)ex0h[j]; e1[j] = (float)ex1h[j];
      f0[j] = (float)ek0h[j]; f1[j] = (float)ek1h[j];
      w[j]  = (float)wvh[j];
    }
#pragma unroll
    for (int p = 0; p < 4; ++p) {
      int j0 = 2 * p, j1 = 2 * p + 1;
      {
        float A = fmaf(e0[j0], f0[j0], 1.f), B = fmaf(e0[j1], f0[j1], 1.f);
        a00 = fmaf(fmaf(w[j0], B, w[j1] * A), RCPF(A * B), a00);
      }
      {
        float A = fmaf(e0[j0], f1[j0], 1.f), B = fmaf(e0[j1], f1[j1], 1.f);
        a01 = fmaf(fmaf(w[j0], B, w[j1] * A), RCPF(A * B), a01);
      }
      {
        float A = fmaf(e1[j0], f0[j0], 1.f), B = fmaf(e1[j1], f0[j1], 1.f);
        a10 = fmaf(fmaf(w[j0], B, w[j1] * A), RCPF(A * B), a10);
      }
      {
        float A = fmaf(e1[j0], f1[j0], 1.f), B = fmaf(e1[j1], f1[j1], 1.f);
        a11 = fmaf(fmaf(w[j0], B, w[j1] * A), RCPF(A * B), a11);
      }
    }
  }

  // ---- softmax over k: 2 k in-thread x 8 kg-lanes (shuffle width 8) ----
  const float l2e = 1.4426950408889634f;
  {
    float m = fmaxf(a00, a01);
#pragma unroll
    for (int s = 1; s < 8; s <<= 1) m = fmaxf(m, __shfl_xor(m, s, 8));
    float p0 = EXP2F((a00 - m) * l2e), p1 = EXP2F((a01 - m) * l2e);
    float sum = p0 + p1;
#pragma unroll
    for (int s = 1; s < 8; s <<= 1) sum += __shfl_xor(sum, s, 8);
    float inv = RCPF(sum);
    float2 o = make_float2(p0 * inv, p1 * inv);
    *(float2*)&out[(size_t)(row0 + rp) * 16 + k0p] = o;
  }
  {
    float m = fmaxf(a10, a11);
#pragma unroll
    for (int s = 1; s < 8; s <<= 1) m = fmaxf(m, __shfl_xor(m, s, 8));
    float p0 = EXP2F((a10 - m) * l2e), p1 = EXP2F((a11 - m) * l2e);
    float sum = p0 + p1;
#pragma unroll
    for (int s = 1; s < 8; s <<= 1) sum += __shfl_xor(sum, s, 8);
    float inv = RCPF(sum);
    float2 o = make_float2(p0 * inv, p1 * inv);
    *(float2*)&out[(size_t)(row0 + rp + 1) * 16 + k0p] = o;
  }
}

// ---------------------------------------------------------------------------
extern "C" void kernel_launch(void* const* d_in, const int* in_sizes, int n_in,
                              void* d_out, int out_size, void* d_ws, size_t ws_size,
                              hipStream_t stream) {
  const float* x   = (const float*)d_in[0];
  const float* mu  = (const float*)d_in[1];
  const float* tau = (const float*)d_in[2];
  const float* W1  = (const float*)d_in[3];
  const float* b1  = (const float*)d_in[4];
  const float* W2  = (const float*)d_in[5];
  // b2 (d_in[6]) and sum(W2) are k-uniform -> cancelled by softmax.
  float* out = (float*)d_out;
  (void)in_sizes; (void)n_in; (void)out_size; (void)d_ws; (void)ws_size;

  fused_kernel<<<512, 512, 0, stream>>>(x, mu, tau, W1, b1, W2, out);
}